// Round 8
// baseline (4285.348 us; speedup 1.0000x reference)
//
#include <hip/hip_runtime.h>
#include <math.h>

#define B_    8
#define V_    4096
#define P_    2048
#define N_    32
#define INDIM 256
#define H_    8
#define D_    32
#define L_    2
#define MLP_  128
#define RES_  100
#define HD_   256
#define EPS_  1e-5f
#define SCALE_ 0.17677669529663687f
#define LOG_RES_ 4.605170185988091f

#define LDP_  132   // LDS row stride: 132%32==4, 16B aligned

// ---------------------------------------------------------------------------
// att_value init: att[b,p,:] = encoded[b, pp[p], :] @ Wds + bds
// ---------------------------------------------------------------------------
__global__ __launch_bounds__(256) void k_init_att(
    const float* __restrict__ encoded, const int* __restrict__ pp,
    const float* __restrict__ Wds, const float* __restrict__ bds,
    float* __restrict__ att)
{
    __shared__ float xs[32][INDIM];
    const int t = threadIdx.x;
    const int g0 = blockIdx.x * 32;
    for (int idx = t; idx < 32 * INDIM; idx += 256) {
        int r = idx >> 8, i = idx & 255;
        int g = g0 + r;
        int b = g >> 11, pl = g & 2047;
        xs[r][i] = encoded[((size_t)b * V_ + pp[pl]) * INDIM + i];
    }
    __syncthreads();
    const int jg = t & 63, rg = t >> 6;
    const int j = jg * 4;
    float acc[8][4];
    #pragma unroll
    for (int r = 0; r < 8; ++r)
        #pragma unroll
        for (int c = 0; c < 4; ++c) acc[r][c] = 0.f;
    for (int i = 0; i < INDIM; ++i) {
        const float4 w = *(const float4*)&Wds[(size_t)i * HD_ + j];
        #pragma unroll
        for (int r = 0; r < 8; ++r) {
            float x = xs[rg * 8 + r][i];
            acc[r][0] += x * w.x; acc[r][1] += x * w.y;
            acc[r][2] += x * w.z; acc[r][3] += x * w.w;
        }
    }
    const float4 bb = *(const float4*)&bds[j];
    #pragma unroll
    for (int r = 0; r < 8; ++r) {
        float4 o;
        o.x = acc[r][0] + bb.x; o.y = acc[r][1] + bb.y;
        o.z = acc[r][2] + bb.z; o.w = acc[r][3] + bb.w;
        *(float4*)&att[((size_t)(g0 + rg * 8 + r)) * HD_ + j] = o;
    }
}

// ---------------------------------------------------------------------------
// kv MLP: 32-row blocks, thread tile 2 rows x 8 cols, 4 blocks/CU (33.9 KB).
// BOTH streams software-pipelined one 4-K group ahead (weights: 8 float4;
// x-fragments: 2 ds_read_b128) -> no exposed LDS/L2 latency in steady state.
// amdgpu_waves_per_eu(4,4): VGPR budget exactly 128; max=4 removes the
// allocator's incentive to clamp to 64 (rounds 3/4 failure mode).
// grid: (B*V/32, H, 2).
// ---------------------------------------------------------------------------

// 16 FMAs: one x scalar per row (X0,X1) times 8 weight cols (WLO,WHI)
#define KSTEP(X0, X1, WLO, WHI)                                              \
    acc0[0] += (X0)*WLO.x; acc0[1] += (X0)*WLO.y;                            \
    acc0[2] += (X0)*WLO.z; acc0[3] += (X0)*WLO.w;                            \
    acc0[4] += (X0)*WHI.x; acc0[5] += (X0)*WHI.y;                            \
    acc0[6] += (X0)*WHI.z; acc0[7] += (X0)*WHI.w;                            \
    acc1[0] += (X1)*WLO.x; acc1[1] += (X1)*WLO.y;                            \
    acc1[2] += (X1)*WLO.z; acc1[3] += (X1)*WLO.w;                            \
    acc1[4] += (X1)*WHI.x; acc1[5] += (X1)*WHI.y;                            \
    acc1[6] += (X1)*WHI.z; acc1[7] += (X1)*WHI.w;

#define GRPC()                                                               \
      KSTEP(xc0.x, xc1.x, w0, w1);                                           \
      KSTEP(xc0.y, xc1.y, w2, w3);                                           \
      KSTEP(xc0.z, xc1.z, w4, w5);                                           \
      KSTEP(xc0.w, xc1.w, w6, w7);

// 128-deep pipelined dot block: weights AND x prefetched one group ahead
#define PIPE128(WPTR, LDW, XS)                                               \
    { const float* wp_ = (WPTR);                                             \
      float4 w0 = *(const float4*)&wp_[0];                                   \
      float4 w1 = *(const float4*)&wp_[4];                                   \
      float4 w2 = *(const float4*)&wp_[(size_t)(LDW)];                       \
      float4 w3 = *(const float4*)&wp_[(size_t)(LDW) + 4];                   \
      float4 w4 = *(const float4*)&wp_[2*(size_t)(LDW)];                     \
      float4 w5 = *(const float4*)&wp_[2*(size_t)(LDW) + 4];                 \
      float4 w6 = *(const float4*)&wp_[3*(size_t)(LDW)];                     \
      float4 w7 = *(const float4*)&wp_[3*(size_t)(LDW) + 4];                 \
      float4 xc0 = *(const float4*)&XS[r0][0];                               \
      float4 xc1 = *(const float4*)&XS[r0 + 1][0];                           \
      for (int i_ = 0; i_ < 124; i_ += 4) {                                  \
        float4 n0 = *(const float4*)&wp_[(size_t)(i_+4)*(LDW)];              \
        float4 n1 = *(const float4*)&wp_[(size_t)(i_+4)*(LDW) + 4];          \
        float4 n2 = *(const float4*)&wp_[(size_t)(i_+5)*(LDW)];              \
        float4 n3 = *(const float4*)&wp_[(size_t)(i_+5)*(LDW) + 4];          \
        float4 n4 = *(const float4*)&wp_[(size_t)(i_+6)*(LDW)];              \
        float4 n5 = *(const float4*)&wp_[(size_t)(i_+6)*(LDW) + 4];          \
        float4 n6 = *(const float4*)&wp_[(size_t)(i_+7)*(LDW)];              \
        float4 n7 = *(const float4*)&wp_[(size_t)(i_+7)*(LDW) + 4];          \
        float4 nx0 = *(const float4*)&XS[r0][i_ + 4];                        \
        float4 nx1 = *(const float4*)&XS[r0 + 1][i_ + 4];                    \
        GRPC();                                                              \
        w0=n0; w1=n1; w2=n2; w3=n3; w4=n4; w5=n5; w6=n6; w7=n7;              \
        xc0=nx0; xc1=nx1;                                                    \
      }                                                                      \
      GRPC();                                                                \
    }

__global__ __launch_bounds__(256)
__attribute__((amdgpu_waves_per_eu(4, 4)))
void k_kv_mlp(
    const float* __restrict__ encoded, const float* __restrict__ true_u,
    const float* __restrict__ kW1, const float* __restrict__ kb1,
    const float* __restrict__ kW2, const float* __restrict__ kb2,
    const float* __restrict__ kW3, const float* __restrict__ kb3,
    const float* __restrict__ vW1, const float* __restrict__ vb1,
    const float* __restrict__ vW2, const float* __restrict__ vb2,
    const float* __restrict__ vW3, const float* __restrict__ vb3,
    float* __restrict__ keys, float* __restrict__ values)
{
    __shared__ float bufA[32 * LDP_];   // x cols 0..127, then h1
    __shared__ float bufB[32 * LDP_];   // x cols 128..255, then h2
    __shared__ float us[32];
    float (*xa)[LDP_] = (float (*)[LDP_])bufA;
    float (*xb)[LDP_] = (float (*)[LDP_])bufB;

    const int t  = threadIdx.x;
    const int g0 = blockIdx.x * 32;
    const int b  = g0 >> 12;
    const int v0 = g0 & (V_ - 1);
    const int hh = blockIdx.y;
    const int kv = blockIdx.z;
    const float* W1 = (kv ? vW1 : kW1) + (size_t)hh * (INDIM + 1) * MLP_;
    const float* b1 = (kv ? vb1 : kb1) + hh * MLP_;
    const float* W2 = (kv ? vW2 : kW2) + (size_t)hh * MLP_ * MLP_;
    const float* b2 = (kv ? vb2 : kb2) + hh * MLP_;
    const float* W3 = (kv ? vW3 : kW3) + (size_t)hh * MLP_ * D_;
    const float* b3 = (kv ? vb3 : kb3) + hh * D_;
    float* outp = kv ? values : keys;

    // stage x: chunk0 -> bufA, chunk1 -> bufB (4 float4 each per thread)
    const float* xgb = encoded + ((size_t)b * V_ + v0) * INDIM;
    #pragma unroll
    for (int k = 0; k < 4; ++k) {
        int idx = t + (k << 8);           // 0..1023
        int row = idx >> 5, c4 = (idx & 31) << 2;
        *(float4*)&xa[row][c4] = *(const float4*)&xgb[(size_t)row * INDIM + c4];
        *(float4*)&xb[row][c4] = *(const float4*)&xgb[(size_t)row * INDIM + 128 + c4];
    }
    if (t < 32) us[t] = true_u[(size_t)b * V_ + v0 + t];
    __syncthreads();

    const int cg = t & 15, vg = t >> 4;
    const int m  = cg << 3;      // 8 output cols
    const int r0 = vg << 1;      // 2 rows (0..31)

    float acc0[8], acc1[8];
    #pragma unroll
    for (int c = 0; c < 8; ++c) { acc0[c] = 0.f; acc1[c] = 0.f; }

    // ---- stage 1: K rows 0..127 (bufA), 128..255 (bufB), u row 256
    PIPE128(W1 + m, MLP_, xa);
    PIPE128(W1 + (size_t)128 * MLP_ + m, MLP_, xb);
    {
        const float4 wu0 = *(const float4*)&W1[(size_t)256 * MLP_ + m];
        const float4 wu1 = *(const float4*)&W1[(size_t)256 * MLP_ + m + 4];
        const float u0 = us[r0], u1 = us[r0 + 1];
        KSTEP(u0, u1, wu0, wu1);
    }
    __syncthreads();   // all x reads done; bufA free for h1
    {
        const float4 bb0 = *(const float4*)&b1[m];
        const float4 bb1 = *(const float4*)&b1[m + 4];
        float4 o;
        o.x = fmaxf(acc0[0] + bb0.x, 0.f); o.y = fmaxf(acc0[1] + bb0.y, 0.f);
        o.z = fmaxf(acc0[2] + bb0.z, 0.f); o.w = fmaxf(acc0[3] + bb0.w, 0.f);
        *(float4*)&xa[r0][m] = o;
        o.x = fmaxf(acc0[4] + bb1.x, 0.f); o.y = fmaxf(acc0[5] + bb1.y, 0.f);
        o.z = fmaxf(acc0[6] + bb1.z, 0.f); o.w = fmaxf(acc0[7] + bb1.w, 0.f);
        *(float4*)&xa[r0][m + 4] = o;
        o.x = fmaxf(acc1[0] + bb0.x, 0.f); o.y = fmaxf(acc1[1] + bb0.y, 0.f);
        o.z = fmaxf(acc1[2] + bb0.z, 0.f); o.w = fmaxf(acc1[3] + bb0.w, 0.f);
        *(float4*)&xa[r0 + 1][m] = o;
        o.x = fmaxf(acc1[4] + bb1.x, 0.f); o.y = fmaxf(acc1[5] + bb1.y, 0.f);
        o.z = fmaxf(acc1[6] + bb1.z, 0.f); o.w = fmaxf(acc1[7] + bb1.w, 0.f);
        *(float4*)&xa[r0 + 1][m + 4] = o;
    }
    __syncthreads();   // h1 complete in bufA

    // ---- stage 2: 128 -> 128 relu; read bufA (h1), write bufB (h2)
    #pragma unroll
    for (int c = 0; c < 8; ++c) { acc0[c] = 0.f; acc1[c] = 0.f; }
    PIPE128(W2 + m, MLP_, xa);
    __syncthreads();   // all h1 reads done; bufB free for h2
    {
        const float4 bb0 = *(const float4*)&b2[m];
        const float4 bb1 = *(const float4*)&b2[m + 4];
        float4 o;
        o.x = fmaxf(acc0[0] + bb0.x, 0.f); o.y = fmaxf(acc0[1] + bb0.y, 0.f);
        o.z = fmaxf(acc0[2] + bb0.z, 0.f); o.w = fmaxf(acc0[3] + bb0.w, 0.f);
        *(float4*)&xb[r0][m] = o;
        o.x = fmaxf(acc0[4] + bb1.x, 0.f); o.y = fmaxf(acc0[5] + bb1.y, 0.f);
        o.z = fmaxf(acc0[6] + bb1.z, 0.f); o.w = fmaxf(acc0[7] + bb1.w, 0.f);
        *(float4*)&xb[r0][m + 4] = o;
        o.x = fmaxf(acc1[0] + bb0.x, 0.f); o.y = fmaxf(acc1[1] + bb0.y, 0.f);
        o.z = fmaxf(acc1[2] + bb0.z, 0.f); o.w = fmaxf(acc1[3] + bb0.w, 0.f);
        *(float4*)&xb[r0 + 1][m] = o;
        o.x = fmaxf(acc1[4] + bb1.x, 0.f); o.y = fmaxf(acc1[5] + bb1.y, 0.f);
        o.z = fmaxf(acc1[6] + bb1.z, 0.f); o.w = fmaxf(acc1[7] + bb1.w, 0.f);
        *(float4*)&xb[r0 + 1][m + 4] = o;
    }
    __syncthreads();   // h2 complete in bufB

    // ---- stage 3: 128 -> 32, write out (thread = row vq, 4 cols)
    {
        const int dg = t & 7, vq = t >> 3;
        const int d = dg << 2;
        float a0 = 0.f, a1 = 0.f, a2 = 0.f, a3 = 0.f;
        const float* wp = W3 + d;
        float4 wa = *(const float4*)&wp[0 * D_];
        float4 wb = *(const float4*)&wp[1 * D_];
        float4 wc = *(const float4*)&wp[2 * D_];
        float4 wd = *(const float4*)&wp[3 * D_];
        for (int i = 0; i < 124; i += 4) {
            float4 na = *(const float4*)&wp[(size_t)(i + 4) * D_];
            float4 nb = *(const float4*)&wp[(size_t)(i + 5) * D_];
            float4 nc = *(const float4*)&wp[(size_t)(i + 6) * D_];
            float4 nd = *(const float4*)&wp[(size_t)(i + 7) * D_];
            const float4 xv = *(const float4*)&xb[vq][i];
            a0 += xv.x*wa.x; a1 += xv.x*wa.y; a2 += xv.x*wa.z; a3 += xv.x*wa.w;
            a0 += xv.y*wb.x; a1 += xv.y*wb.y; a2 += xv.y*wb.z; a3 += xv.y*wb.w;
            a0 += xv.z*wc.x; a1 += xv.z*wc.y; a2 += xv.z*wc.z; a3 += xv.z*wc.w;
            a0 += xv.w*wd.x; a1 += xv.w*wd.y; a2 += xv.w*wd.z; a3 += xv.w*wd.w;
            wa = na; wb = nb; wc = nc; wd = nd;
        }
        {
            const float4 xv = *(const float4*)&xb[vq][124];
            a0 += xv.x*wa.x; a1 += xv.x*wa.y; a2 += xv.x*wa.z; a3 += xv.x*wa.w;
            a0 += xv.y*wb.x; a1 += xv.y*wb.y; a2 += xv.y*wb.z; a3 += xv.y*wb.w;
            a0 += xv.z*wc.x; a1 += xv.z*wc.y; a2 += xv.z*wc.z; a3 += xv.z*wc.w;
            a0 += xv.w*wd.x; a1 += xv.w*wd.y; a2 += xv.w*wd.z; a3 += xv.w*wd.w;
        }
        float4 o;
        o.x = a0 + b3[d + 0]; o.y = a1 + b3[d + 1];
        o.z = a2 + b3[d + 2]; o.w = a3 + b3[d + 3];
        *(float4*)&outp[((size_t)b * V_ + v0 + vq) * HD_ + hh * D_ + d] = o;
    }
}

// ---------------------------------------------------------------------------
// fused neighbor attention + residual + LN1.  one block per (b,p).
// ---------------------------------------------------------------------------
__global__ __launch_bounds__(256) void k_attn_ln(
    const float* __restrict__ keys, const float* __restrict__ values,
    const int* __restrict__ nbr,
    const float* __restrict__ g, const float* __restrict__ bet,
    float* __restrict__ att)
{
    __shared__ float qs[HD_];
    __shared__ float ws[H_][N_];
    __shared__ int   idx[N_];
    __shared__ float red[4];
    const int t = threadIdx.x;
    const int bp = blockIdx.x;
    const int b = bp >> 11;
    const int p = bp & (P_ - 1);
    if (t < N_) idx[t] = nbr[p * N_ + t];
    qs[t] = att[(size_t)bp * HD_ + t];
    __syncthreads();

    const int hh = t >> 5;
    {
        const int n = t & 31;
        const float4* kp = (const float4*)(keys + ((size_t)b * V_ + idx[n]) * HD_ + hh * D_);
        float s = 0.f;
        #pragma unroll
        for (int j = 0; j < 8; ++j) {
            const float4 kk = kp[j];
            s += qs[hh * D_ + j * 4 + 0] * kk.x + qs[hh * D_ + j * 4 + 1] * kk.y +
                 qs[hh * D_ + j * 4 + 2] * kk.z + qs[hh * D_ + j * 4 + 3] * kk.w;
        }
        s *= SCALE_;
        float m = s;
        #pragma unroll
        for (int off = 16; off; off >>= 1) m = fmaxf(m, __shfl_xor(m, off, 32));
        float e = expf(s - m);
        float sum = e;
        #pragma unroll
        for (int off = 16; off; off >>= 1) sum += __shfl_xor(sum, off, 32);
        ws[hh][n] = e / sum;
    }
    __syncthreads();

    float a = 0.f;
    {
        const int d = t & 31;
        const float* vb = values + (size_t)b * V_ * HD_ + hh * D_ + d;
        #pragma unroll
        for (int n2 = 0; n2 < N_; ++n2)
            a += ws[hh][n2] * vb[(size_t)idx[n2] * HD_];
    }

    float x = qs[t] + a;
    float s1 = x;
    #pragma unroll
    for (int off = 32; off; off >>= 1) s1 += __shfl_xor(s1, off, 64);
    if ((t & 63) == 0) red[t >> 6] = s1;
    __syncthreads();
    float mean = (red[0] + red[1] + red[2] + red[3]) * (1.f / HD_);
    __syncthreads();
    float dx = x - mean;
    float v2 = dx * dx;
    #pragma unroll
    for (int off = 32; off; off >>= 1) v2 += __shfl_xor(v2, off, 64);
    if ((t & 63) == 0) red[t >> 6] = v2;
    __syncthreads();
    float var = (red[0] + red[1] + red[2] + red[3]) * (1.f / HD_);
    att[(size_t)bp * HD_ + t] = dx * rsqrtf(var + EPS_) * g[t] + bet[t];
}

// ---------------------------------------------------------------------------
// fused FF (256->256 relu -> 256) + residual + LN2.  32 rows per block.
// ---------------------------------------------------------------------------
#define FP_ (HD_ + 4)
__global__ __launch_bounds__(256) void k_ff_ln(
    const float* __restrict__ W1, const float* __restrict__ b1,
    const float* __restrict__ W2, const float* __restrict__ b2,
    const float* __restrict__ g, const float* __restrict__ bet,
    float* __restrict__ att)
{
    __shared__ float xs[32][FP_];
    __shared__ float hs[32][FP_];
    const int t = threadIdx.x;
    const int g0 = blockIdx.x * 32;
    for (int idx = t; idx < 32 * HD_; idx += 256) {
        int r = idx >> 8, i = idx & 255;
        xs[r][i] = att[((size_t)(g0 + r)) * HD_ + i];
    }
    __syncthreads();
    const int jg = t & 63, rg = t >> 6;
    const int j = jg * 4;

    float acc[8][4];
    #pragma unroll
    for (int r = 0; r < 8; ++r)
        #pragma unroll
        for (int c = 0; c < 4; ++c) acc[r][c] = 0.f;
    for (int i = 0; i < HD_; ++i) {
        const float4 w = *(const float4*)&W1[(size_t)i * HD_ + j];
        #pragma unroll
        for (int r = 0; r < 8; ++r) {
            float x = xs[rg * 8 + r][i];
            acc[r][0] += x * w.x; acc[r][1] += x * w.y;
            acc[r][2] += x * w.z; acc[r][3] += x * w.w;
        }
    }
    {
        const float4 bb = *(const float4*)&b1[j];
        #pragma unroll
        for (int r = 0; r < 8; ++r) {
            float4 o;
            o.x = fmaxf(acc[r][0] + bb.x, 0.f); o.y = fmaxf(acc[r][1] + bb.y, 0.f);
            o.z = fmaxf(acc[r][2] + bb.z, 0.f); o.w = fmaxf(acc[r][3] + bb.w, 0.f);
            *(float4*)&hs[rg * 8 + r][j] = o;
        }
    }
    __syncthreads();

    #pragma unroll
    for (int r = 0; r < 8; ++r)
        #pragma unroll
        for (int c = 0; c < 4; ++c) acc[r][c] = 0.f;
    for (int i = 0; i < HD_; ++i) {
        const float4 w = *(const float4*)&W2[(size_t)i * HD_ + j];
        #pragma unroll
        for (int r = 0; r < 8; ++r) {
            float x = hs[rg * 8 + r][i];
            acc[r][0] += x * w.x; acc[r][1] += x * w.y;
            acc[r][2] += x * w.z; acc[r][3] += x * w.w;
        }
    }
    float y[8][4];
    {
        const float4 bb = *(const float4*)&b2[j];
        #pragma unroll
        for (int r = 0; r < 8; ++r) {
            y[r][0] = acc[r][0] + bb.x + xs[rg * 8 + r][j + 0];
            y[r][1] = acc[r][1] + bb.y + xs[rg * 8 + r][j + 1];
            y[r][2] = acc[r][2] + bb.z + xs[rg * 8 + r][j + 2];
            y[r][3] = acc[r][3] + bb.w + xs[rg * 8 + r][j + 3];
        }
    }
    __syncthreads();
    #pragma unroll
    for (int r = 0; r < 8; ++r) {
        float4 o; o.x = y[r][0]; o.y = y[r][1]; o.z = y[r][2]; o.w = y[r][3];
        *(float4*)&xs[rg * 8 + r][j] = o;
    }
    __syncthreads();

    const int rr = t >> 3, k = t & 7;
    float s = 0.f;
    for (int i = 0; i < 32; ++i) s += xs[rr][k + 8 * i];
    #pragma unroll
    for (int off = 4; off; off >>= 1) s += __shfl_xor(s, off, 8);
    float mean = s * (1.f / HD_);
    float vs = 0.f;
    for (int i = 0; i < 32; ++i) { float d = xs[rr][k + 8 * i] - mean; vs += d * d; }
    #pragma unroll
    for (int off = 4; off; off >>= 1) vs += __shfl_xor(vs, off, 8);
    float rstd = rsqrtf(vs * (1.f / HD_) + EPS_);
    for (int i = 0; i < 32; ++i) {
        int jj = k + 8 * i;
        att[((size_t)(g0 + rr)) * HD_ + jj] =
            (xs[rr][jj] - mean) * rstd * g[jj] + bet[jj];
    }
}

// ---------------------------------------------------------------------------
// decoder (256->128 relu ->128 relu ->100) + log_softmax + NLL partials
// ---------------------------------------------------------------------------
__global__ __launch_bounds__(256) void k_dec_loss(
    const float* __restrict__ att, const float* __restrict__ true_u,
    const int* __restrict__ pp,
    const float* __restrict__ dW1, const float* __restrict__ db1,
    const float* __restrict__ dW2, const float* __restrict__ db2,
    const float* __restrict__ dW3, const float* __restrict__ db3,
    float* __restrict__ partial)
{
    __shared__ float xs[32][HD_];
    __shared__ float h1s[32][MLP_];
    __shared__ float h2s[32][MLP_];
    __shared__ float ls[32][104];
    __shared__ float rowloss[32];
    const int t = threadIdx.x;
    const int g0 = blockIdx.x * 32;
    for (int idx = t; idx < 32 * HD_; idx += 256) {
        int r = idx >> 8, i = idx & 255;
        xs[r][i] = att[((size_t)(g0 + r)) * HD_ + i];
    }
    __syncthreads();
    const int jg = t & 31, rg = t >> 5;
    const int j = jg * 4;

    {
        float acc[4][4];
        #pragma unroll
        for (int r = 0; r < 4; ++r)
            #pragma unroll
            for (int c = 0; c < 4; ++c) acc[r][c] = 0.f;
        for (int i = 0; i < HD_; ++i) {
            const float4 w = *(const float4*)&dW1[(size_t)i * MLP_ + j];
            #pragma unroll
            for (int r = 0; r < 4; ++r) {
                float x = xs[rg * 4 + r][i];
                acc[r][0] += x * w.x; acc[r][1] += x * w.y;
                acc[r][2] += x * w.z; acc[r][3] += x * w.w;
            }
        }
        const float4 bb = *(const float4*)&db1[j];
        #pragma unroll
        for (int r = 0; r < 4; ++r) {
            float4 o;
            o.x = fmaxf(acc[r][0] + bb.x, 0.f); o.y = fmaxf(acc[r][1] + bb.y, 0.f);
            o.z = fmaxf(acc[r][2] + bb.z, 0.f); o.w = fmaxf(acc[r][3] + bb.w, 0.f);
            *(float4*)&h1s[rg * 4 + r][j] = o;
        }
    }
    __syncthreads();
    {
        float acc[4][4];
        #pragma unroll
        for (int r = 0; r < 4; ++r)
            #pragma unroll
            for (int c = 0; c < 4; ++c) acc[r][c] = 0.f;
        for (int i = 0; i < MLP_; ++i) {
            const float4 w = *(const float4*)&dW2[(size_t)i * MLP_ + j];
            #pragma unroll
            for (int r = 0; r < 4; ++r) {
                float x = h1s[rg * 4 + r][i];
                acc[r][0] += x * w.x; acc[r][1] += x * w.y;
                acc[r][2] += x * w.z; acc[r][3] += x * w.w;
            }
        }
        const float4 bb = *(const float4*)&db2[j];
        #pragma unroll
        for (int r = 0; r < 4; ++r) {
            float4 o;
            o.x = fmaxf(acc[r][0] + bb.x, 0.f); o.y = fmaxf(acc[r][1] + bb.y, 0.f);
            o.z = fmaxf(acc[r][2] + bb.z, 0.f); o.w = fmaxf(acc[r][3] + bb.w, 0.f);
            *(float4*)&h2s[rg * 4 + r][j] = o;
        }
    }
    __syncthreads();
    {
        const bool act = (jg < 25);
        float acc[4][4];
        #pragma unroll
        for (int r = 0; r < 4; ++r)
            #pragma unroll
            for (int c = 0; c < 4; ++c) acc[r][c] = 0.f;
        for (int i = 0; i < MLP_; ++i) {
            float4 w = make_float4(0.f, 0.f, 0.f, 0.f);
            if (act) w = *(const float4*)&dW3[(size_t)i * RES_ + j];
            #pragma unroll
            for (int r = 0; r < 4; ++r) {
                float x = h2s[rg * 4 + r][i];
                acc[r][0] += x * w.x; acc[r][1] += x * w.y;
                acc[r][2] += x * w.z; acc[r][3] += x * w.w;
            }
        }
        if (act) {
            const float4 bb = *(const float4*)&db3[j];
            #pragma unroll
            for (int r = 0; r < 4; ++r) {
                ls[rg * 4 + r][j + 0] = acc[r][0] + bb.x;
                ls[rg * 4 + r][j + 1] = acc[r][1] + bb.y;
                ls[rg * 4 + r][j + 2] = acc[r][2] + bb.z;
                ls[rg * 4 + r][j + 3] = acc[r][3] + bb.w;
            }
        }
    }
    __syncthreads();

    const int rr = t >> 3, k = t & 7;
    float mx = -1e30f;
    for (int q = k; q < RES_; q += 8) mx = fmaxf(mx, ls[rr][q]);
    #pragma unroll
    for (int off = 4; off; off >>= 1) mx = fmaxf(mx, __shfl_xor(mx, off, 8));
    float se = 0.f;
    for (int q = k; q < RES_; q += 8) se += expf(ls[rr][q] - mx);
    #pragma unroll
    for (int off = 4; off; off >>= 1) se += __shfl_xor(se, off, 8);
    if (k == 0) {
        int gg = g0 + rr;
        int b = gg >> 11, pl = gg & (P_ - 1);
        float tu = true_u[(size_t)b * V_ + pp[pl]];
        int tgt = (int)floorf(tu * (float)RES_);
        tgt = tgt < 0 ? 0 : (tgt > RES_ - 1 ? RES_ - 1 : tgt);
        rowloss[rr] = LOG_RES_ + ls[rr][tgt] - mx - logf(se);
    }
    __syncthreads();
    if (t == 0) {
        float s = 0.f;
        for (int r2 = 0; r2 < 32; ++r2) s += rowloss[r2];
        partial[blockIdx.x] = -s;
    }
}

__global__ __launch_bounds__(64) void k_reduce_loss(
    const float* __restrict__ partial, float* __restrict__ loss)
{
    const int b = blockIdx.x, t = threadIdx.x;
    float s = partial[b * 64 + t];
    #pragma unroll
    for (int off = 32; off; off >>= 1) s += __shfl_xor(s, off, 64);
    if (t == 0) loss[b] = s;
}

// ---------------------------------------------------------------------------
extern "C" void kernel_launch(void* const* d_in, const int* in_sizes, int n_in,
                              void* d_out, int out_size, void* d_ws, size_t ws_size,
                              hipStream_t stream)
{
    (void)in_sizes; (void)n_in; (void)out_size; (void)ws_size;
    const float* encoded = (const float*)d_in[0];
    const float* true_u  = (const float*)d_in[1];
    const int*   pp      = (const int*)d_in[2];
    const int*   nbr     = (const int*)d_in[3];
    const float* Wds     = (const float*)d_in[4];
    const float* bds     = (const float*)d_in[5];
    const float* kW1 = (const float*)d_in[6];
    const float* kb1 = (const float*)d_in[7];
    const float* kW2 = (const float*)d_in[8];
    const float* kb2 = (const float*)d_in[9];
    const float* kW3 = (const float*)d_in[10];
    const float* kb3 = (const float*)d_in[11];
    const float* vW1 = (const float*)d_in[12];
    const float* vb1 = (const float*)d_in[13];
    const float* vW2 = (const float*)d_in[14];
    const float* vb2 = (const float*)d_in[15];
    const float* vW3 = (const float*)d_in[16];
    const float* vb3 = (const float*)d_in[17];
    const float* dW1 = (const float*)d_in[18];
    const float* db1 = (const float*)d_in[19];
    const float* dW2 = (const float*)d_in[20];
    const float* db2 = (const float*)d_in[21];
    const float* dW3 = (const float*)d_in[22];
    const float* db3 = (const float*)d_in[23];
    const float* ln1g = (const float*)d_in[24];
    const float* ln1b = (const float*)d_in[25];
    const float* ln2g = (const float*)d_in[26];
    const float* ln2b = (const float*)d_in[27];
    const float* fW1 = (const float*)d_in[28];
    const float* fb1 = (const float*)d_in[29];
    const float* fW2 = (const float*)d_in[30];
    const float* fb2 = (const float*)d_in[31];

    float* att  = (float*)d_ws;                       // B*P*HD
    float* keys = att + (size_t)B_ * P_ * HD_;        // B*V*HD
    float* vals = keys + (size_t)B_ * V_ * HD_;       // B*V*HD
    float* part = vals + (size_t)B_ * V_ * HD_;       // 512 partials

    k_init_att<<<dim3((B_ * P_) / 32), 256, 0, stream>>>(encoded, pp, Wds, bds, att);

    for (int l = 0; l < L_; ++l) {
        k_kv_mlp<<<dim3((B_ * V_) / 32, H_, 2), 256, 0, stream>>>(
            encoded, true_u,
            kW1 + (size_t)l * H_ * (INDIM + 1) * MLP_, kb1 + l * H_ * MLP_,
            kW2 + (size_t)l * H_ * MLP_ * MLP_,        kb2 + l * H_ * MLP_,
            kW3 + (size_t)l * H_ * MLP_ * D_,          kb3 + l * H_ * D_,
            vW1 + (size_t)l * H_ * (INDIM + 1) * MLP_, vb1 + l * H_ * MLP_,
            vW2 + (size_t)l * H_ * MLP_ * MLP_,        vb2 + l * H_ * MLP_,
            vW3 + (size_t)l * H_ * MLP_ * D_,          vb3 + l * H_ * D_,
            keys, vals);
        k_attn_ln<<<dim3(B_ * P_), 256, 0, stream>>>(
            keys, vals, nbr, ln1g + l * HD_, ln1b + l * HD_, att);
        k_ff_ln<<<dim3((B_ * P_) / 32), 256, 0, stream>>>(
            fW1 + (size_t)l * HD_ * HD_, fb1 + l * HD_,
            fW2 + (size_t)l * HD_ * HD_, fb2 + l * HD_,
            ln2g + l * HD_, ln2b + l * HD_, att);
    }

    k_dec_loss<<<dim3((B_ * P_) / 32), 256, 0, stream>>>(
        att, true_u, pp, dW1, db1, dW2, db2, dW3, db3, part);
    k_reduce_loss<<<dim3(B_), 64, 0, stream>>>(part, (float*)d_out);
}

// Round 9
// 2429.700 us; speedup vs baseline: 1.7637x; 1.7637x over previous
//
#include <hip/hip_runtime.h>
#include <math.h>

#define B_    8
#define V_    4096
#define P_    2048
#define N_    32
#define INDIM 256
#define H_    8
#define D_    32
#define L_    2
#define MLP_  128
#define RES_  100
#define HD_   256
#define EPS_  1e-5f
#define SCALE_ 0.17677669529663687f
#define LOG_RES_ 4.605170185988091f

#define LDP_  132   // LDS row stride: 132%32==4, 16B aligned

// ---------------------------------------------------------------------------
// att_value init: att[b,p,:] = encoded[b, pp[p], :] @ Wds + bds
// ---------------------------------------------------------------------------
__global__ __launch_bounds__(256) void k_init_att(
    const float* __restrict__ encoded, const int* __restrict__ pp,
    const float* __restrict__ Wds, const float* __restrict__ bds,
    float* __restrict__ att)
{
    __shared__ float xs[32][INDIM];
    const int t = threadIdx.x;
    const int g0 = blockIdx.x * 32;
    for (int idx = t; idx < 32 * INDIM; idx += 256) {
        int r = idx >> 8, i = idx & 255;
        int g = g0 + r;
        int b = g >> 11, pl = g & 2047;
        xs[r][i] = encoded[((size_t)b * V_ + pp[pl]) * INDIM + i];
    }
    __syncthreads();
    const int jg = t & 63, rg = t >> 6;
    const int j = jg * 4;
    float acc[8][4];
    #pragma unroll
    for (int r = 0; r < 8; ++r)
        #pragma unroll
        for (int c = 0; c < 4; ++c) acc[r][c] = 0.f;
    for (int i = 0; i < INDIM; ++i) {
        const float4 w = *(const float4*)&Wds[(size_t)i * HD_ + j];
        #pragma unroll
        for (int r = 0; r < 8; ++r) {
            float x = xs[rg * 8 + r][i];
            acc[r][0] += x * w.x; acc[r][1] += x * w.y;
            acc[r][2] += x * w.z; acc[r][3] += x * w.w;
        }
    }
    const float4 bb = *(const float4*)&bds[j];
    #pragma unroll
    for (int r = 0; r < 8; ++r) {
        float4 o;
        o.x = acc[r][0] + bb.x; o.y = acc[r][1] + bb.y;
        o.z = acc[r][2] + bb.z; o.w = acc[r][3] + bb.w;
        *(float4*)&att[((size_t)(g0 + rg * 8 + r)) * HD_ + j] = o;
    }
}

// ---------------------------------------------------------------------------
// kv MLP: 64-row blocks, thread tile 4 rows x 8 cols, 2 blocks/CU (67.8 KB).
// ROUND-6 MEASURED BASE (88 VGPR, no spill, 1135us) + ONE CHANGE:
// x-fragments now prefetched one 4-K group ahead alongside the weights.
// 128 FMAs (256 issue-cy) cover both 200cy L2 (weights) and 120cy LDS (x).
// waves_per_eu(2,2): the only attribute measured to unlock >64 VGPRs.
// grid: (B*V/64, H, 2).
// ---------------------------------------------------------------------------

// 8 FMAs: one x scalar times cols m..m+7 (WL,WH) into acc row R
#define FMA8(R, XSC, WL, WH)                                                 \
    acc[R][0] += (XSC)*WL.x; acc[R][1] += (XSC)*WL.y;                        \
    acc[R][2] += (XSC)*WL.z; acc[R][3] += (XSC)*WL.w;                        \
    acc[R][4] += (XSC)*WH.x; acc[R][5] += (XSC)*WH.y;                        \
    acc[R][6] += (XSC)*WH.z; acc[R][7] += (XSC)*WH.w;

// one 4-K group (128 FMAs) from preloaded x (xv0..xv3) and w (w0..w7)
#define GRPC4()                                                              \
      FMA8(0, xv0.x, w0, w1); FMA8(1, xv1.x, w0, w1);                        \
      FMA8(2, xv2.x, w0, w1); FMA8(3, xv3.x, w0, w1);                        \
      FMA8(0, xv0.y, w2, w3); FMA8(1, xv1.y, w2, w3);                        \
      FMA8(2, xv2.y, w2, w3); FMA8(3, xv3.y, w2, w3);                        \
      FMA8(0, xv0.z, w4, w5); FMA8(1, xv1.z, w4, w5);                        \
      FMA8(2, xv2.z, w4, w5); FMA8(3, xv3.z, w4, w5);                        \
      FMA8(0, xv0.w, w6, w7); FMA8(1, xv1.w, w6, w7);                        \
      FMA8(2, xv2.w, w6, w7); FMA8(3, xv3.w, w6, w7);

// 128-deep dot block: weights AND x prefetched one 4-K group ahead
#define PIPE128(WPTR, LDW, XS)                                               \
    { const float* wp_ = (WPTR);                                             \
      float4 w0 = *(const float4*)&wp_[0];                                   \
      float4 w1 = *(const float4*)&wp_[4];                                   \
      float4 w2 = *(const float4*)&wp_[(size_t)(LDW)];                       \
      float4 w3 = *(const float4*)&wp_[(size_t)(LDW) + 4];                   \
      float4 w4 = *(const float4*)&wp_[2*(size_t)(LDW)];                     \
      float4 w5 = *(const float4*)&wp_[2*(size_t)(LDW) + 4];                 \
      float4 w6 = *(const float4*)&wp_[3*(size_t)(LDW)];                     \
      float4 w7 = *(const float4*)&wp_[3*(size_t)(LDW) + 4];                 \
      float4 xv0 = *(const float4*)&XS[r0 + 0][0];                           \
      float4 xv1 = *(const float4*)&XS[r0 + 1][0];                           \
      float4 xv2 = *(const float4*)&XS[r0 + 2][0];                           \
      float4 xv3 = *(const float4*)&XS[r0 + 3][0];                           \
      for (int i_ = 0; i_ < 124; i_ += 4) {                                  \
        float4 n0 = *(const float4*)&wp_[(size_t)(i_+4)*(LDW)];              \
        float4 n1 = *(const float4*)&wp_[(size_t)(i_+4)*(LDW) + 4];          \
        float4 n2 = *(const float4*)&wp_[(size_t)(i_+5)*(LDW)];              \
        float4 n3 = *(const float4*)&wp_[(size_t)(i_+5)*(LDW) + 4];          \
        float4 n4 = *(const float4*)&wp_[(size_t)(i_+6)*(LDW)];              \
        float4 n5 = *(const float4*)&wp_[(size_t)(i_+6)*(LDW) + 4];          \
        float4 n6 = *(const float4*)&wp_[(size_t)(i_+7)*(LDW)];              \
        float4 n7 = *(const float4*)&wp_[(size_t)(i_+7)*(LDW) + 4];          \
        float4 nx0 = *(const float4*)&XS[r0 + 0][i_ + 4];                    \
        float4 nx1 = *(const float4*)&XS[r0 + 1][i_ + 4];                    \
        float4 nx2 = *(const float4*)&XS[r0 + 2][i_ + 4];                    \
        float4 nx3 = *(const float4*)&XS[r0 + 3][i_ + 4];                    \
        GRPC4();                                                             \
        w0=n0; w1=n1; w2=n2; w3=n3; w4=n4; w5=n5; w6=n6; w7=n7;              \
        xv0=nx0; xv1=nx1; xv2=nx2; xv3=nx3;                                  \
      }                                                                      \
      GRPC4();                                                               \
    }

__global__ __launch_bounds__(256)
__attribute__((amdgpu_waves_per_eu(2, 2)))
void k_kv_mlp(
    const float* __restrict__ encoded, const float* __restrict__ true_u,
    const float* __restrict__ kW1, const float* __restrict__ kb1,
    const float* __restrict__ kW2, const float* __restrict__ kb2,
    const float* __restrict__ kW3, const float* __restrict__ kb3,
    const float* __restrict__ vW1, const float* __restrict__ vb1,
    const float* __restrict__ vW2, const float* __restrict__ vb2,
    const float* __restrict__ vW3, const float* __restrict__ vb3,
    float* __restrict__ keys, float* __restrict__ values)
{
    __shared__ float bufA[64 * LDP_];   // x cols 0..127, then h1
    __shared__ float bufB[64 * LDP_];   // x cols 128..255, then h2
    __shared__ float us[64];
    float (*xa)[LDP_] = (float (*)[LDP_])bufA;
    float (*xb)[LDP_] = (float (*)[LDP_])bufB;

    const int t  = threadIdx.x;
    const int g0 = blockIdx.x * 64;
    const int b  = g0 >> 12;
    const int v0 = g0 & (V_ - 1);
    const int hh = blockIdx.y;
    const int kv = blockIdx.z;
    const float* W1 = (kv ? vW1 : kW1) + (size_t)hh * (INDIM + 1) * MLP_;
    const float* b1 = (kv ? vb1 : kb1) + hh * MLP_;
    const float* W2 = (kv ? vW2 : kW2) + (size_t)hh * MLP_ * MLP_;
    const float* b2 = (kv ? vb2 : kb2) + hh * MLP_;
    const float* W3 = (kv ? vW3 : kW3) + (size_t)hh * MLP_ * D_;
    const float* b3 = (kv ? vb3 : kb3) + hh * D_;
    float* outp = kv ? values : keys;

    // stage x: chunk0 -> bufA, chunk1 -> bufB (8 float4 each per thread)
    const float* xgb = encoded + ((size_t)b * V_ + v0) * INDIM;
    #pragma unroll
    for (int k = 0; k < 8; ++k) {
        int idx = t + (k << 8);           // 0..2047
        int row = idx >> 5, c4 = (idx & 31) << 2;
        *(float4*)&xa[row][c4] = *(const float4*)&xgb[(size_t)row * INDIM + c4];
        *(float4*)&xb[row][c4] = *(const float4*)&xgb[(size_t)row * INDIM + 128 + c4];
    }
    if (t < 64) us[t] = true_u[(size_t)b * V_ + v0 + t];
    __syncthreads();

    const int cg = t & 15, vg = t >> 4;
    const int m  = cg << 3;      // 8 output cols
    const int r0 = vg << 2;      // 4 rows

    float acc[4][8];
    #pragma unroll
    for (int r = 0; r < 4; ++r)
        #pragma unroll
        for (int c = 0; c < 8; ++c) acc[r][c] = 0.f;

    // ---- stage 1: K rows 0..127 (bufA), 128..255 (bufB), u row 256
    PIPE128(W1 + m, MLP_, xa);
    PIPE128(W1 + (size_t)128 * MLP_ + m, MLP_, xb);
    {
        const float4 wu0 = *(const float4*)&W1[(size_t)256 * MLP_ + m];
        const float4 wu1 = *(const float4*)&W1[(size_t)256 * MLP_ + m + 4];
        #pragma unroll
        for (int r = 0; r < 4; ++r) {
            const float uu = us[r0 + r];
            FMA8(r, uu, wu0, wu1);
        }
    }
    __syncthreads();   // all x reads done; bufA free for h1
    {
        const float4 bb0 = *(const float4*)&b1[m];
        const float4 bb1 = *(const float4*)&b1[m + 4];
        #pragma unroll
        for (int r = 0; r < 4; ++r) {
            float4 o;
            o.x = fmaxf(acc[r][0] + bb0.x, 0.f); o.y = fmaxf(acc[r][1] + bb0.y, 0.f);
            o.z = fmaxf(acc[r][2] + bb0.z, 0.f); o.w = fmaxf(acc[r][3] + bb0.w, 0.f);
            *(float4*)&xa[r0 + r][m] = o;
            o.x = fmaxf(acc[r][4] + bb1.x, 0.f); o.y = fmaxf(acc[r][5] + bb1.y, 0.f);
            o.z = fmaxf(acc[r][6] + bb1.z, 0.f); o.w = fmaxf(acc[r][7] + bb1.w, 0.f);
            *(float4*)&xa[r0 + r][m + 4] = o;
        }
    }
    __syncthreads();   // h1 complete in bufA

    // ---- stage 2: 128 -> 128 relu; read bufA (h1), write bufB (h2)
    #pragma unroll
    for (int r = 0; r < 4; ++r)
        #pragma unroll
        for (int c = 0; c < 8; ++c) acc[r][c] = 0.f;
    PIPE128(W2 + m, MLP_, xa);
    __syncthreads();   // all h1 reads done; bufB free for h2
    {
        const float4 bb0 = *(const float4*)&b2[m];
        const float4 bb1 = *(const float4*)&b2[m + 4];
        #pragma unroll
        for (int r = 0; r < 4; ++r) {
            float4 o;
            o.x = fmaxf(acc[r][0] + bb0.x, 0.f); o.y = fmaxf(acc[r][1] + bb0.y, 0.f);
            o.z = fmaxf(acc[r][2] + bb0.z, 0.f); o.w = fmaxf(acc[r][3] + bb0.w, 0.f);
            *(float4*)&xb[r0 + r][m] = o;
            o.x = fmaxf(acc[r][4] + bb1.x, 0.f); o.y = fmaxf(acc[r][5] + bb1.y, 0.f);
            o.z = fmaxf(acc[r][6] + bb1.z, 0.f); o.w = fmaxf(acc[r][7] + bb1.w, 0.f);
            *(float4*)&xb[r0 + r][m + 4] = o;
        }
    }
    __syncthreads();   // h2 complete in bufB

    // ---- stage 3: 128 -> 32; thread = (row vq=t>>2, 8 cols at d=(t&3)*8)
    {
        const int vq = t >> 2, d = (t & 3) << 3;
        float a[8];
        #pragma unroll
        for (int c = 0; c < 8; ++c) a[c] = 0.f;
        const float* wp = W3 + d;
        float4 w0 = *(const float4*)&wp[0];
        float4 w1 = *(const float4*)&wp[4];
        float4 w2 = *(const float4*)&wp[D_];
        float4 w3 = *(const float4*)&wp[D_ + 4];
        float4 w4 = *(const float4*)&wp[2 * D_];
        float4 w5 = *(const float4*)&wp[2 * D_ + 4];
        float4 w6 = *(const float4*)&wp[3 * D_];
        float4 w7 = *(const float4*)&wp[3 * D_ + 4];
        for (int i = 0; i < 124; i += 4) {
            float4 n0 = *(const float4*)&wp[(size_t)(i + 4) * D_];
            float4 n1 = *(const float4*)&wp[(size_t)(i + 4) * D_ + 4];
            float4 n2 = *(const float4*)&wp[(size_t)(i + 5) * D_];
            float4 n3 = *(const float4*)&wp[(size_t)(i + 5) * D_ + 4];
            float4 n4 = *(const float4*)&wp[(size_t)(i + 6) * D_];
            float4 n5 = *(const float4*)&wp[(size_t)(i + 6) * D_ + 4];
            float4 n6 = *(const float4*)&wp[(size_t)(i + 7) * D_];
            float4 n7 = *(const float4*)&wp[(size_t)(i + 7) * D_ + 4];
            const float4 xv = *(const float4*)&xb[vq][i];
            a[0]+=xv.x*w0.x; a[1]+=xv.x*w0.y; a[2]+=xv.x*w0.z; a[3]+=xv.x*w0.w;
            a[4]+=xv.x*w1.x; a[5]+=xv.x*w1.y; a[6]+=xv.x*w1.z; a[7]+=xv.x*w1.w;
            a[0]+=xv.y*w2.x; a[1]+=xv.y*w2.y; a[2]+=xv.y*w2.z; a[3]+=xv.y*w2.w;
            a[4]+=xv.y*w3.x; a[5]+=xv.y*w3.y; a[6]+=xv.y*w3.z; a[7]+=xv.y*w3.w;
            a[0]+=xv.z*w4.x; a[1]+=xv.z*w4.y; a[2]+=xv.z*w4.z; a[3]+=xv.z*w4.w;
            a[4]+=xv.z*w5.x; a[5]+=xv.z*w5.y; a[6]+=xv.z*w5.z; a[7]+=xv.z*w5.w;
            a[0]+=xv.w*w6.x; a[1]+=xv.w*w6.y; a[2]+=xv.w*w6.z; a[3]+=xv.w*w6.w;
            a[4]+=xv.w*w7.x; a[5]+=xv.w*w7.y; a[6]+=xv.w*w7.z; a[7]+=xv.w*w7.w;
            w0=n0; w1=n1; w2=n2; w3=n3; w4=n4; w5=n5; w6=n6; w7=n7;
        }
        {
            const float4 xv = *(const float4*)&xb[vq][124];
            a[0]+=xv.x*w0.x; a[1]+=xv.x*w0.y; a[2]+=xv.x*w0.z; a[3]+=xv.x*w0.w;
            a[4]+=xv.x*w1.x; a[5]+=xv.x*w1.y; a[6]+=xv.x*w1.z; a[7]+=xv.x*w1.w;
            a[0]+=xv.y*w2.x; a[1]+=xv.y*w2.y; a[2]+=xv.y*w2.z; a[3]+=xv.y*w2.w;
            a[4]+=xv.y*w3.x; a[5]+=xv.y*w3.y; a[6]+=xv.y*w3.z; a[7]+=xv.y*w3.w;
            a[0]+=xv.z*w4.x; a[1]+=xv.z*w4.y; a[2]+=xv.z*w4.z; a[3]+=xv.z*w4.w;
            a[4]+=xv.z*w5.x; a[5]+=xv.z*w5.y; a[6]+=xv.z*w5.z; a[7]+=xv.z*w5.w;
            a[0]+=xv.w*w6.x; a[1]+=xv.w*w6.y; a[2]+=xv.w*w6.z; a[3]+=xv.w*w6.w;
            a[4]+=xv.w*w7.x; a[5]+=xv.w*w7.y; a[6]+=xv.w*w7.z; a[7]+=xv.w*w7.w;
        }
        float4 o;
        float* op = &outp[((size_t)b * V_ + v0 + vq) * HD_ + hh * D_ + d];
        o.x = a[0] + b3[d + 0]; o.y = a[1] + b3[d + 1];
        o.z = a[2] + b3[d + 2]; o.w = a[3] + b3[d + 3];
        *(float4*)&op[0] = o;
        o.x = a[4] + b3[d + 4]; o.y = a[5] + b3[d + 5];
        o.z = a[6] + b3[d + 6]; o.w = a[7] + b3[d + 7];
        *(float4*)&op[4] = o;
    }
}

// ---------------------------------------------------------------------------
// fused neighbor attention + residual + LN1.  one block per (b,p).
// ---------------------------------------------------------------------------
__global__ __launch_bounds__(256) void k_attn_ln(
    const float* __restrict__ keys, const float* __restrict__ values,
    const int* __restrict__ nbr,
    const float* __restrict__ g, const float* __restrict__ bet,
    float* __restrict__ att)
{
    __shared__ float qs[HD_];
    __shared__ float ws[H_][N_];
    __shared__ int   idx[N_];
    __shared__ float red[4];
    const int t = threadIdx.x;
    const int bp = blockIdx.x;
    const int b = bp >> 11;
    const int p = bp & (P_ - 1);
    if (t < N_) idx[t] = nbr[p * N_ + t];
    qs[t] = att[(size_t)bp * HD_ + t];
    __syncthreads();

    const int hh = t >> 5;
    {
        const int n = t & 31;
        const float4* kp = (const float4*)(keys + ((size_t)b * V_ + idx[n]) * HD_ + hh * D_);
        float s = 0.f;
        #pragma unroll
        for (int j = 0; j < 8; ++j) {
            const float4 kk = kp[j];
            s += qs[hh * D_ + j * 4 + 0] * kk.x + qs[hh * D_ + j * 4 + 1] * kk.y +
                 qs[hh * D_ + j * 4 + 2] * kk.z + qs[hh * D_ + j * 4 + 3] * kk.w;
        }
        s *= SCALE_;
        float m = s;
        #pragma unroll
        for (int off = 16; off; off >>= 1) m = fmaxf(m, __shfl_xor(m, off, 32));
        float e = expf(s - m);
        float sum = e;
        #pragma unroll
        for (int off = 16; off; off >>= 1) sum += __shfl_xor(sum, off, 32);
        ws[hh][n] = e / sum;
    }
    __syncthreads();

    float a = 0.f;
    {
        const int d = t & 31;
        const float* vb = values + (size_t)b * V_ * HD_ + hh * D_ + d;
        #pragma unroll
        for (int n2 = 0; n2 < N_; ++n2)
            a += ws[hh][n2] * vb[(size_t)idx[n2] * HD_];
    }

    float x = qs[t] + a;
    float s1 = x;
    #pragma unroll
    for (int off = 32; off; off >>= 1) s1 += __shfl_xor(s1, off, 64);
    if ((t & 63) == 0) red[t >> 6] = s1;
    __syncthreads();
    float mean = (red[0] + red[1] + red[2] + red[3]) * (1.f / HD_);
    __syncthreads();
    float dx = x - mean;
    float v2 = dx * dx;
    #pragma unroll
    for (int off = 32; off; off >>= 1) v2 += __shfl_xor(v2, off, 64);
    if ((t & 63) == 0) red[t >> 6] = v2;
    __syncthreads();
    float var = (red[0] + red[1] + red[2] + red[3]) * (1.f / HD_);
    att[(size_t)bp * HD_ + t] = dx * rsqrtf(var + EPS_) * g[t] + bet[t];
}

// ---------------------------------------------------------------------------
// fused FF (256->256 relu -> 256) + residual + LN2.  32 rows per block.
// ---------------------------------------------------------------------------
#define FP_ (HD_ + 4)
__global__ __launch_bounds__(256) void k_ff_ln(
    const float* __restrict__ W1, const float* __restrict__ b1,
    const float* __restrict__ W2, const float* __restrict__ b2,
    const float* __restrict__ g, const float* __restrict__ bet,
    float* __restrict__ att)
{
    __shared__ float xs[32][FP_];
    __shared__ float hs[32][FP_];
    const int t = threadIdx.x;
    const int g0 = blockIdx.x * 32;
    for (int idx = t; idx < 32 * HD_; idx += 256) {
        int r = idx >> 8, i = idx & 255;
        xs[r][i] = att[((size_t)(g0 + r)) * HD_ + i];
    }
    __syncthreads();
    const int jg = t & 63, rg = t >> 6;
    const int j = jg * 4;

    float acc[8][4];
    #pragma unroll
    for (int r = 0; r < 8; ++r)
        #pragma unroll
        for (int c = 0; c < 4; ++c) acc[r][c] = 0.f;
    for (int i = 0; i < HD_; ++i) {
        const float4 w = *(const float4*)&W1[(size_t)i * HD_ + j];
        #pragma unroll
        for (int r = 0; r < 8; ++r) {
            float x = xs[rg * 8 + r][i];
            acc[r][0] += x * w.x; acc[r][1] += x * w.y;
            acc[r][2] += x * w.z; acc[r][3] += x * w.w;
        }
    }
    {
        const float4 bb = *(const float4*)&b1[j];
        #pragma unroll
        for (int r = 0; r < 8; ++r) {
            float4 o;
            o.x = fmaxf(acc[r][0] + bb.x, 0.f); o.y = fmaxf(acc[r][1] + bb.y, 0.f);
            o.z = fmaxf(acc[r][2] + bb.z, 0.f); o.w = fmaxf(acc[r][3] + bb.w, 0.f);
            *(float4*)&hs[rg * 8 + r][j] = o;
        }
    }
    __syncthreads();

    #pragma unroll
    for (int r = 0; r < 8; ++r)
        #pragma unroll
        for (int c = 0; c < 4; ++c) acc[r][c] = 0.f;
    for (int i = 0; i < HD_; ++i) {
        const float4 w = *(const float4*)&W2[(size_t)i * HD_ + j];
        #pragma unroll
        for (int r = 0; r < 8; ++r) {
            float x = hs[rg * 8 + r][i];
            acc[r][0] += x * w.x; acc[r][1] += x * w.y;
            acc[r][2] += x * w.z; acc[r][3] += x * w.w;
        }
    }
    float y[8][4];
    {
        const float4 bb = *(const float4*)&b2[j];
        #pragma unroll
        for (int r = 0; r < 8; ++r) {
            y[r][0] = acc[r][0] + bb.x + xs[rg * 8 + r][j + 0];
            y[r][1] = acc[r][1] + bb.y + xs[rg * 8 + r][j + 1];
            y[r][2] = acc[r][2] + bb.z + xs[rg * 8 + r][j + 2];
            y[r][3] = acc[r][3] + bb.w + xs[rg * 8 + r][j + 3];
        }
    }
    __syncthreads();
    #pragma unroll
    for (int r = 0; r < 8; ++r) {
        float4 o; o.x = y[r][0]; o.y = y[r][1]; o.z = y[r][2]; o.w = y[r][3];
        *(float4*)&xs[rg * 8 + r][j] = o;
    }
    __syncthreads();

    const int rr = t >> 3, k = t & 7;
    float s = 0.f;
    for (int i = 0; i < 32; ++i) s += xs[rr][k + 8 * i];
    #pragma unroll
    for (int off = 4; off; off >>= 1) s += __shfl_xor(s, off, 8);
    float mean = s * (1.f / HD_);
    float vs = 0.f;
    for (int i = 0; i < 32; ++i) { float d = xs[rr][k + 8 * i] - mean; vs += d * d; }
    #pragma unroll
    for (int off = 4; off; off >>= 1) vs += __shfl_xor(vs, off, 8);
    float rstd = rsqrtf(vs * (1.f / HD_) + EPS_);
    for (int i = 0; i < 32; ++i) {
        int jj = k + 8 * i;
        att[((size_t)(g0 + rr)) * HD_ + jj] =
            (xs[rr][jj] - mean) * rstd * g[jj] + bet[jj];
    }
}

// ---------------------------------------------------------------------------
// decoder (256->128 relu ->128 relu ->100) + log_softmax + NLL partials
// ---------------------------------------------------------------------------
__global__ __launch_bounds__(256) void k_dec_loss(
    const float* __restrict__ att, const float* __restrict__ true_u,
    const int* __restrict__ pp,
    const float* __restrict__ dW1, const float* __restrict__ db1,
    const float* __restrict__ dW2, const float* __restrict__ db2,
    const float* __restrict__ dW3, const float* __restrict__ db3,
    float* __restrict__ partial)
{
    __shared__ float xs[32][HD_];
    __shared__ float h1s[32][MLP_];
    __shared__ float h2s[32][MLP_];
    __shared__ float ls[32][104];
    __shared__ float rowloss[32];
    const int t = threadIdx.x;
    const int g0 = blockIdx.x * 32;
    for (int idx = t; idx < 32 * HD_; idx += 256) {
        int r = idx >> 8, i = idx & 255;
        xs[r][i] = att[((size_t)(g0 + r)) * HD_ + i];
    }
    __syncthreads();
    const int jg = t & 31, rg = t >> 5;
    const int j = jg * 4;

    {
        float acc[4][4];
        #pragma unroll
        for (int r = 0; r < 4; ++r)
            #pragma unroll
            for (int c = 0; c < 4; ++c) acc[r][c] = 0.f;
        for (int i = 0; i < HD_; ++i) {
            const float4 w = *(const float4*)&dW1[(size_t)i * MLP_ + j];
            #pragma unroll
            for (int r = 0; r < 4; ++r) {
                float x = xs[rg * 4 + r][i];
                acc[r][0] += x * w.x; acc[r][1] += x * w.y;
                acc[r][2] += x * w.z; acc[r][3] += x * w.w;
            }
        }
        const float4 bb = *(const float4*)&db1[j];
        #pragma unroll
        for (int r = 0; r < 4; ++r) {
            float4 o;
            o.x = fmaxf(acc[r][0] + bb.x, 0.f); o.y = fmaxf(acc[r][1] + bb.y, 0.f);
            o.z = fmaxf(acc[r][2] + bb.z, 0.f); o.w = fmaxf(acc[r][3] + bb.w, 0.f);
            *(float4*)&h1s[rg * 4 + r][j] = o;
        }
    }
    __syncthreads();
    {
        float acc[4][4];
        #pragma unroll
        for (int r = 0; r < 4; ++r)
            #pragma unroll
            for (int c = 0; c < 4; ++c) acc[r][c] = 0.f;
        for (int i = 0; i < MLP_; ++i) {
            const float4 w = *(const float4*)&dW2[(size_t)i * MLP_ + j];
            #pragma unroll
            for (int r = 0; r < 4; ++r) {
                float x = h1s[rg * 4 + r][i];
                acc[r][0] += x * w.x; acc[r][1] += x * w.y;
                acc[r][2] += x * w.z; acc[r][3] += x * w.w;
            }
        }
        const float4 bb = *(const float4*)&db2[j];
        #pragma unroll
        for (int r = 0; r < 4; ++r) {
            float4 o;
            o.x = fmaxf(acc[r][0] + bb.x, 0.f); o.y = fmaxf(acc[r][1] + bb.y, 0.f);
            o.z = fmaxf(acc[r][2] + bb.z, 0.f); o.w = fmaxf(acc[r][3] + bb.w, 0.f);
            *(float4*)&h2s[rg * 4 + r][j] = o;
        }
    }
    __syncthreads();
    {
        const bool act = (jg < 25);
        float acc[4][4];
        #pragma unroll
        for (int r = 0; r < 4; ++r)
            #pragma unroll
            for (int c = 0; c < 4; ++c) acc[r][c] = 0.f;
        for (int i = 0; i < MLP_; ++i) {
            float4 w = make_float4(0.f, 0.f, 0.f, 0.f);
            if (act) w = *(const float4*)&dW3[(size_t)i * RES_ + j];
            #pragma unroll
            for (int r = 0; r < 4; ++r) {
                float x = h2s[rg * 4 + r][i];
                acc[r][0] += x * w.x; acc[r][1] += x * w.y;
                acc[r][2] += x * w.z; acc[r][3] += x * w.w;
            }
        }
        if (act) {
            const float4 bb = *(const float4*)&db3[j];
            #pragma unroll
            for (int r = 0; r < 4; ++r) {
                ls[rg * 4 + r][j + 0] = acc[r][0] + bb.x;
                ls[rg * 4 + r][j + 1] = acc[r][1] + bb.y;
                ls[rg * 4 + r][j + 2] = acc[r][2] + bb.z;
                ls[rg * 4 + r][j + 3] = acc[r][3] + bb.w;
            }
        }
    }
    __syncthreads();

    const int rr = t >> 3, k = t & 7;
    float mx = -1e30f;
    for (int q = k; q < RES_; q += 8) mx = fmaxf(mx, ls[rr][q]);
    #pragma unroll
    for (int off = 4; off; off >>= 1) mx = fmaxf(mx, __shfl_xor(mx, off, 8));
    float se = 0.f;
    for (int q = k; q < RES_; q += 8) se += expf(ls[rr][q] - mx);
    #pragma unroll
    for (int off = 4; off; off >>= 1) se += __shfl_xor(se, off, 8);
    if (k == 0) {
        int gg = g0 + rr;
        int b = gg >> 11, pl = gg & (P_ - 1);
        float tu = true_u[(size_t)b * V_ + pp[pl]];
        int tgt = (int)floorf(tu * (float)RES_);
        tgt = tgt < 0 ? 0 : (tgt > RES_ - 1 ? RES_ - 1 : tgt);
        rowloss[rr] = LOG_RES_ + ls[rr][tgt] - mx - logf(se);
    }
    __syncthreads();
    if (t == 0) {
        float s = 0.f;
        for (int r2 = 0; r2 < 32; ++r2) s += rowloss[r2];
        partial[blockIdx.x] = -s;
    }
}

__global__ __launch_bounds__(64) void k_reduce_loss(
    const float* __restrict__ partial, float* __restrict__ loss)
{
    const int b = blockIdx.x, t = threadIdx.x;
    float s = partial[b * 64 + t];
    #pragma unroll
    for (int off = 32; off; off >>= 1) s += __shfl_xor(s, off, 64);
    if (t == 0) loss[b] = s;
}

// ---------------------------------------------------------------------------
extern "C" void kernel_launch(void* const* d_in, const int* in_sizes, int n_in,
                              void* d_out, int out_size, void* d_ws, size_t ws_size,
                              hipStream_t stream)
{
    (void)in_sizes; (void)n_in; (void)out_size; (void)ws_size;
    const float* encoded = (const float*)d_in[0];
    const float* true_u  = (const float*)d_in[1];
    const int*   pp      = (const int*)d_in[2];
    const int*   nbr     = (const int*)d_in[3];
    const float* Wds     = (const float*)d_in[4];
    const float* bds     = (const float*)d_in[5];
    const float* kW1 = (const float*)d_in[6];
    const float* kb1 = (const float*)d_in[7];
    const float* kW2 = (const float*)d_in[8];
    const float* kb2 = (const float*)d_in[9];
    const float* kW3 = (const float*)d_in[10];
    const float* kb3 = (const float*)d_in[11];
    const float* vW1 = (const float*)d_in[12];
    const float* vb1 = (const float*)d_in[13];
    const float* vW2 = (const float*)d_in[14];
    const float* vb2 = (const float*)d_in[15];
    const float* vW3 = (const float*)d_in[16];
    const float* vb3 = (const float*)d_in[17];
    const float* dW1 = (const float*)d_in[18];
    const float* db1 = (const float*)d_in[19];
    const float* dW2 = (const float*)d_in[20];
    const float* db2 = (const float*)d_in[21];
    const float* dW3 = (const float*)d_in[22];
    const float* db3 = (const float*)d_in[23];
    const float* ln1g = (const float*)d_in[24];
    const float* ln1b = (const float*)d_in[25];
    const float* ln2g = (const float*)d_in[26];
    const float* ln2b = (const float*)d_in[27];
    const float* fW1 = (const float*)d_in[28];
    const float* fb1 = (const float*)d_in[29];
    const float* fW2 = (const float*)d_in[30];
    const float* fb2 = (const float*)d_in[31];

    float* att  = (float*)d_ws;                       // B*P*HD
    float* keys = att + (size_t)B_ * P_ * HD_;        // B*V*HD
    float* vals = keys + (size_t)B_ * V_ * HD_;       // B*V*HD
    float* part = vals + (size_t)B_ * V_ * HD_;       // 512 partials

    k_init_att<<<dim3((B_ * P_) / 32), 256, 0, stream>>>(encoded, pp, Wds, bds, att);

    for (int l = 0; l < L_; ++l) {
        k_kv_mlp<<<dim3((B_ * V_) / 64, H_, 2), 256, 0, stream>>>(
            encoded, true_u,
            kW1 + (size_t)l * H_ * (INDIM + 1) * MLP_, kb1 + l * H_ * MLP_,
            kW2 + (size_t)l * H_ * MLP_ * MLP_,        kb2 + l * H_ * MLP_,
            kW3 + (size_t)l * H_ * MLP_ * D_,          kb3 + l * H_ * D_,
            vW1 + (size_t)l * H_ * (INDIM + 1) * MLP_, vb1 + l * H_ * MLP_,
            vW2 + (size_t)l * H_ * MLP_ * MLP_,        vb2 + l * H_ * MLP_,
            vW3 + (size_t)l * H_ * MLP_ * D_,          vb3 + l * H_ * D_,
            keys, vals);
        k_attn_ln<<<dim3(B_ * P_), 256, 0, stream>>>(
            keys, vals, nbr, ln1g + l * HD_, ln1b + l * HD_, att);
        k_ff_ln<<<dim3((B_ * P_) / 32), 256, 0, stream>>>(
            fW1 + (size_t)l * HD_ * HD_, fb1 + l * HD_,
            fW2 + (size_t)l * HD_ * HD_, fb2 + l * HD_,
            ln2g + l * HD_, ln2b + l * HD_, att);
    }

    k_dec_loss<<<dim3((B_ * P_) / 32), 256, 0, stream>>>(
        att, true_u, pp, dW1, db1, dW2, db2, dW3, db3, part);
    k_reduce_loss<<<dim3(B_), 64, 0, stream>>>(part, (float*)d_out);
}